// Round 3
// baseline (398.625 us; speedup 1.0000x reference)
//
#include <hip/hip_runtime.h>
#include <cstddef>
#include <cstdint>

// Problem constants (from reference)
#define B_ 64
#define T_ 2000
#define L_ 400
#define M_ 80
#define EPSF 1e-8f
#define LOG_EPSF -18.420680743952367f   // logf(1e-8)
// GLOBAL_STEP=0 -> progress=0 -> sigma = clip(Lb*0.05, 3, 10)

#define NBLK 2048            // fused-kernel grid
#define TBL_N (B_ * L_)      // 25600 (b, exp_pos) normalizer entries

__device__ inline float waveReduce(float v) {
#pragma unroll
  for (int m = 32; m >= 1; m >>= 1) v += __shfl_xor(v, m, 64);
  return v;
}

// ---- Pass 1: per-(b,epi) Gaussian normalizer table ----
// S(b,epi) = sum_{l<Lb} exp(-0.5 ((l-epi)/sigma_b)^2); store
// {1/(S+eps), log(S+eps), 1/sigma_b, (float)epi} as float4.
__global__ __launch_bounds__(256) void table_kernel(
    const int* __restrict__ text_lengths, float4* __restrict__ tbl) {
  const int lane = threadIdx.x & 63;
  const int wid = (blockIdx.x * 256 + threadIdx.x) >> 6;  // one wave per entry
  if (wid >= TBL_N) return;
  const int b = wid / L_;
  const int epi = wid - b * L_;
  const int Lb = text_lengths[b];
  const float sigma = fminf(fmaxf((float)Lb * 0.05f, 3.0f), 10.0f);
  const float invsig = 1.0f / sigma;
  const float epf = (float)epi;
  float S = 0.f;
#pragma unroll
  for (int k = 0; k < 7; ++k) {
    int l = lane + 64 * k;
    if (l < Lb) {
      float z = ((float)l - epf) * invsig;
      S += __expf(-0.5f * z * z);
    }
  }
  S = waveReduce(S);
  if (lane == 0) {
    float Se = S + EPSF;
    float4 e;
    e.x = 1.0f / Se;
    e.y = __logf(Se);
    e.z = invsig;
    e.w = epf;
    tbl[wid] = e;
  }
}

// ---- Pass 2: fused streaming kernel ----
// Every block grid-strides over mel L1, gate BCE, and the now-elementwise
// attention KL+entropy. No per-row reductions anywhere; 16 B/lane loads.
__global__ __launch_bounds__(256) void fused_kernel(
    const float4* __restrict__ mo, const float4* __restrict__ mp,
    const float4* __restrict__ mt, const float4* __restrict__ gx,
    const float4* __restrict__ gz, const float4* __restrict__ align4,
    const float4* __restrict__ tbl,
    const int* __restrict__ mel_lengths, const int* __restrict__ text_lengths,
    double* __restrict__ partials) {
  const int tid = blockIdx.x * 256 + threadIdx.x;
  const int nthreads = NBLK * 256;

  // ---- mel L1 (masked by t < mel_lengths[b]) ----
  float mel_acc = 0.f;
  const int N4 = B_ * T_ * (M_ / 4);
  for (int i = tid; i < N4; i += nthreads) {
    int row = i / (M_ / 4);        // (b*T + t); 4 packed elems share a row
    int b = row / T_;
    int t = row - b * T_;
    if (t < mel_lengths[b]) {
      float4 a = mo[i], c = mp[i], d = mt[i];
      mel_acc += fabsf(a.x - d.x) + fabsf(a.y - d.y) + fabsf(a.z - d.z) + fabsf(a.w - d.w)
               + fabsf(c.x - d.x) + fabsf(c.y - d.y) + fabsf(c.z - d.z) + fabsf(c.w - d.w);
    }
  }

  // ---- gate BCE-with-logits (float4) ----
  float gate_acc = 0.f;
  for (int i = tid; i < (B_ * T_) / 4; i += nthreads) {
    float4 xv = gx[i], zv = gz[i];
    gate_acc += fmaxf(xv.x, 0.f) - xv.x * zv.x + log1pf(__expf(-fabsf(xv.x)))
              + fmaxf(xv.y, 0.f) - xv.y * zv.y + log1pf(__expf(-fabsf(xv.y)))
              + fmaxf(xv.z, 0.f) - xv.z * zv.z + log1pf(__expf(-fabsf(xv.z)))
              + fmaxf(xv.w, 0.f) - xv.w * zv.w + log1pf(__expf(-fabsf(xv.w)));
  }

  // ---- attention KL + entropy: pure elementwise stream ----
  float kl_acc = 0.f, ent_acc = 0.f;
  const int NA4 = B_ * T_ * (L_ / 4);
  for (int i = tid; i < NA4; i += nthreads) {
    int row = i / (L_ / 4);        // / 100
    int li4 = i - row * (L_ / 4);
    int l0 = li4 * 4;
    int b = row / T_;
    int t = row - b * T_;
    int Lb = text_lengths[b];
    int epi = t * Lb / T_;         // floor-div, nonneg -> matches jnp //
    int lim = Lb - 1;
    if (epi > lim) epi = lim;
    float4 tb = tbl[b * L_ + epi]; // {inv, logSe, invsig, epf} — near-uniform, L1
    float4 a4 = align4[i];
    float av[4] = {a4.x, a4.y, a4.z, a4.w};
#pragma unroll
    for (int j = 0; j < 4; ++j) {
      float as = fmaxf(av[j], EPSF);
      float lp = __logf(as);
      ent_acc -= as * lp;                       // entropy: all l
      int l = l0 + j;
      if (l < Lb) {                             // target==0 outside mask
        float z = ((float)l - tb.w) * tb.z;
        float e = -0.5f * z * z;
        float tgt = __expf(e) * tb.x;           // underflow -> 0 -> matches ref
        float lt = fmaxf(e - tb.y, LOG_EPSF);   // log(max(target,EPS))
        kl_acc += tgt * (lt - lp);
      }
    }
  }

  // ---- block reduction of all 4 quantities ----
  float w0 = waveReduce(mel_acc);
  float w1 = waveReduce(gate_acc);
  float w2 = waveReduce(kl_acc);
  float w3 = waveReduce(ent_acc);
  __shared__ double sh[4][4];
  const int lane = threadIdx.x & 63, wib = threadIdx.x >> 6;
  if (lane == 0) {
    sh[wib][0] = (double)w0; sh[wib][1] = (double)w1;
    sh[wib][2] = (double)w2; sh[wib][3] = (double)w3;
  }
  __syncthreads();
  if (threadIdx.x == 0) {
    partials[blockIdx.x]            = sh[0][0] + sh[1][0] + sh[2][0] + sh[3][0];
    partials[NBLK + blockIdx.x]     = sh[0][1] + sh[1][1] + sh[2][1] + sh[3][1];
    partials[2 * NBLK + blockIdx.x] = sh[0][2] + sh[1][2] + sh[2][2] + sh[3][2];
    partials[3 * NBLK + blockIdx.x] = sh[0][3] + sh[1][3] + sh[2][3] + sh[3][3];
  }
}

// ---------------- finalize ----------------
__device__ double segSum(const double* __restrict__ p, int n, double* sh) {
  double a = 0.0;
  for (int i = threadIdx.x; i < n; i += 256) a += p[i];
  sh[threadIdx.x] = a;
  __syncthreads();
  for (int s = 128; s > 0; s >>= 1) {
    if ((int)threadIdx.x < s) sh[threadIdx.x] += sh[threadIdx.x + s];
    __syncthreads();
  }
  double r = sh[0];
  __syncthreads();
  return r;
}

__global__ __launch_bounds__(256) void finalize_kernel(
    const double* __restrict__ partials, const int* __restrict__ mel_lengths,
    float* __restrict__ out) {
  __shared__ double sh[256];
  double mel_sum  = segSum(partials, NBLK, sh);
  double gate_sum = segSum(partials + NBLK, NBLK, sh);
  double kl_sum   = segSum(partials + 2 * NBLK, NBLK, sh);
  double ent_sum  = segSum(partials + 3 * NBLK, NBLK, sh);
  if (threadIdx.x == 0) {
    long nv = 0;
    for (int b = 0; b < B_; ++b) nv += mel_lengths[b];
    double n_valid = (double)nv * (double)M_;
    float loss_mel  = (float)(mel_sum / n_valid);
    float loss_gate = (float)(gate_sum / (double)(B_ * T_));
    float kl  = (float)(kl_sum / (double)(B_ * T_));
    kl = fminf(kl, 150.0f);
    float ent = (float)(ent_sum / (double)(B_ * T_));
    float ratio = fmaxf(ent / 3.5f, 0.0f);
    float weight = (ent <= 3.5f) ? fmaxf(0.2f, 1.0f * ratio) : 1.0f;
    out[0] = loss_mel + loss_gate + weight * kl;
    out[1] = loss_mel;
    out[2] = loss_gate;
    out[3] = kl;
  }
}

extern "C" void kernel_launch(void* const* d_in, const int* in_sizes, int n_in,
                              void* d_out, int out_size, void* d_ws, size_t ws_size,
                              hipStream_t stream) {
  const float* mel_out_postnet = (const float*)d_in[0];
  const float* mel_out         = (const float*)d_in[1];
  const float* gate_out        = (const float*)d_in[2];
  const float* alignments      = (const float*)d_in[3];
  const float* mel_target      = (const float*)d_in[4];
  const float* gate_target     = (const float*)d_in[5];
  const int*   mel_lengths     = (const int*)d_in[6];
  const int*   text_lengths    = (const int*)d_in[7];
  float* out = (float*)d_out;

  // ws layout: float4 table[TBL_N] (409.6 KB), then double partials (64 KB)
  float4* tbl = (float4*)d_ws;
  double* partials = (double*)((char*)d_ws + TBL_N * sizeof(float4));

  table_kernel<<<dim3((TBL_N * 64 + 255) / 256), dim3(256), 0, stream>>>(
      text_lengths, tbl);
  fused_kernel<<<dim3(NBLK), dim3(256), 0, stream>>>(
      (const float4*)mel_out, (const float4*)mel_out_postnet,
      (const float4*)mel_target, (const float4*)gate_out,
      (const float4*)gate_target, (const float4*)alignments, tbl,
      mel_lengths, text_lengths, partials);
  finalize_kernel<<<dim3(1), dim3(256), 0, stream>>>(partials, mel_lengths, out);
}

// Round 4
// 395.858 us; speedup vs baseline: 1.0070x; 1.0070x over previous
//
#include <hip/hip_runtime.h>
#include <cstddef>
#include <cstdint>

// Problem constants (from reference)
#define B_ 64
#define T_ 2000
#define L_ 400
#define M_ 80
#define EPSF 1e-8f
#define LOG_EPSF -18.420680743952367f   // logf(1e-8)
// GLOBAL_STEP=0 -> progress=0 -> sigma = clip(Lb*0.05, 3, 10)

#define TBL_N (B_ * L_)      // 25600 (b, exp_pos) normalizer entries
#define NROW (B_ * T_)       // 128000 (b,t) rows
#define NBLK 2000            // main grid: 64 rows per block

__device__ inline float waveReduce(float v) {
#pragma unroll
  for (int m = 32; m >= 1; m >>= 1) v += __shfl_xor(v, m, 64);
  return v;
}

// ---- Pass 1: per-(b,epi) Gaussian normalizer S ----
__global__ __launch_bounds__(256) void table_kernel(
    const int* __restrict__ text_lengths, float4* __restrict__ tbl) {
  const int lane = threadIdx.x & 63;
  const int wid = (blockIdx.x * 256 + threadIdx.x) >> 6;  // one wave per entry
  if (wid >= TBL_N) return;
  const int b = wid / L_;
  const int epi = wid - b * L_;
  const int Lb = text_lengths[b];
  const float sigma = fminf(fmaxf((float)Lb * 0.05f, 3.0f), 10.0f);
  const float invsig = 1.0f / sigma;
  const float epf = (float)epi;
  float S = 0.f;
#pragma unroll
  for (int k = 0; k < 7; ++k) {
    int l = lane + 64 * k;
    if (l < Lb) {
      float z = ((float)l - epf) * invsig;
      S += __expf(-0.5f * z * z);
    }
  }
  S = waveReduce(S);
  if (lane == 0) {
    float Se = S + EPSF;
    tbl[wid] = make_float4(1.0f / Se, __logf(Se), invsig, 0.f);
  }
}

// ---- Pass 2: expand to per-row table ----
// rowtbl[p=b*T+t] = {1/(S+eps), log(S+eps), 1/sigma, packed}
// packed = epi | (Lb<<10) | (melvalid<<19)  (< 2^20, exact in float)
__global__ __launch_bounds__(256) void expand_kernel(
    const float4* __restrict__ tbl, const int* __restrict__ text_lengths,
    const int* __restrict__ mel_lengths, float4* __restrict__ rowtbl) {
  int p = blockIdx.x * 256 + threadIdx.x;
  if (p >= NROW) return;
  int b = p / T_;
  int t = p - b * T_;
  int Lb = text_lengths[b];
  int epi = t * Lb / T_;           // floor-div, nonneg -> matches jnp //
  if (epi > Lb - 1) epi = Lb - 1;
  float4 e = tbl[b * L_ + epi];
  int melv = (t < mel_lengths[b]) ? 1 : 0;
  int w = epi | (Lb << 10) | (melv << 19);
  rowtbl[p] = make_float4(e.x, e.y, e.z, (float)w);
}

// ---- Pass 3: main fused kernel ----
// Block owns 64 consecutive (b,t) rows. All loops have compile-time trip
// counts; loads are batched 5-15 deep before use for memory-level parallelism.
__global__ __launch_bounds__(256) void fused_kernel(
    const float4* __restrict__ mo, const float4* __restrict__ mp,
    const float4* __restrict__ mt, const float4* __restrict__ gx,
    const float4* __restrict__ gz, const float4* __restrict__ align4,
    const float4* __restrict__ rowtbl, double* __restrict__ partials) {
  const int tid = threadIdx.x;
  const int base_row = blockIdx.x * 64;
  float mel_acc = 0.f, gate_acc = 0.f, kl_acc = 0.f, ent_acc = 0.f;

  // ---- attention KL + entropy: 6400 float4 per block, 25 per thread ----
  const float4* __restrict__ ab = align4 + (size_t)base_row * (L_ / 4);
  const float4* __restrict__ rt = rowtbl + base_row;
  for (int kk = 0; kk < 5; ++kk) {
    float4 a[5], tb[5];
    int l0[5];
#pragma unroll
    for (int j = 0; j < 5; ++j) {
      int idx = tid + 256 * (kk * 5 + j);          // < 6400
      unsigned r = (unsigned)idx / 100u;           // row within block
      a[j] = ab[idx];
      tb[j] = rt[r];                               // near-wave-uniform, L1
      l0[j] = (idx - (int)r * 100) * 4;
    }
#pragma unroll
    for (int j = 0; j < 5; ++j) {
      int wi = (int)tb[j].w;
      float epf = (float)(wi & 1023);
      int Lb = (wi >> 10) & 511;
      float inv = tb[j].x, logSe = tb[j].y, invsig = tb[j].z;
      float av[4] = {a[j].x, a[j].y, a[j].z, a[j].w};
#pragma unroll
      for (int q = 0; q < 4; ++q) {
        float as = fmaxf(av[q], EPSF);
        float lp = __logf(as);
        ent_acc -= as * lp;                        // entropy: all l
        int l = l0[j] + q;
        if (l < Lb) {                              // target==0 outside mask
          float z = ((float)l - epf) * invsig;
          float e = -0.5f * z * z;
          float tgt = __expf(e) * inv;             // underflow->0 matches ref
          float lt = fmaxf(e - logSe, LOG_EPSF);   // log(max(target,EPS))
          kl_acc += tgt * (lt - lp);
        }
      }
    }
  }

  // ---- mel L1: 1280 float4 per block, 5 per thread ----
  {
    const float4* __restrict__ mob = mo + (size_t)base_row * (M_ / 4);
    const float4* __restrict__ mpb = mp + (size_t)base_row * (M_ / 4);
    const float4* __restrict__ mtb = mt + (size_t)base_row * (M_ / 4);
    float4 A[5], C[5], D[5];
    int mv[5];
#pragma unroll
    for (int j = 0; j < 5; ++j) {
      int idx = tid + 256 * j;                     // < 1280
      unsigned r = (unsigned)idx / 20u;
      A[j] = mob[idx];
      C[j] = mpb[idx];
      D[j] = mtb[idx];
      mv[j] = ((int)rt[r].w) >> 19;                // mel-valid bit
    }
#pragma unroll
    for (int j = 0; j < 5; ++j) {
      if (mv[j]) {
        mel_acc += fabsf(A[j].x - D[j].x) + fabsf(A[j].y - D[j].y)
                 + fabsf(A[j].z - D[j].z) + fabsf(A[j].w - D[j].w)
                 + fabsf(C[j].x - D[j].x) + fabsf(C[j].y - D[j].y)
                 + fabsf(C[j].z - D[j].z) + fabsf(C[j].w - D[j].w);
      }
    }
  }

  // ---- gate BCE: 16 float4 per block ----
  if (tid < 16) {
    float4 xv = gx[base_row / 4 + tid];
    float4 zv = gz[base_row / 4 + tid];
    gate_acc = fmaxf(xv.x, 0.f) - xv.x * zv.x + log1pf(__expf(-fabsf(xv.x)))
             + fmaxf(xv.y, 0.f) - xv.y * zv.y + log1pf(__expf(-fabsf(xv.y)))
             + fmaxf(xv.z, 0.f) - xv.z * zv.z + log1pf(__expf(-fabsf(xv.z)))
             + fmaxf(xv.w, 0.f) - xv.w * zv.w + log1pf(__expf(-fabsf(xv.w)));
  }

  // ---- block reduction of all 4 quantities ----
  float w0 = waveReduce(mel_acc);
  float w1 = waveReduce(gate_acc);
  float w2 = waveReduce(kl_acc);
  float w3 = waveReduce(ent_acc);
  __shared__ double sh[4][4];
  const int lane = threadIdx.x & 63, wib = threadIdx.x >> 6;
  if (lane == 0) {
    sh[wib][0] = (double)w0; sh[wib][1] = (double)w1;
    sh[wib][2] = (double)w2; sh[wib][3] = (double)w3;
  }
  __syncthreads();
  if (tid == 0) {
    partials[blockIdx.x]            = sh[0][0] + sh[1][0] + sh[2][0] + sh[3][0];
    partials[NBLK + blockIdx.x]     = sh[0][1] + sh[1][1] + sh[2][1] + sh[3][1];
    partials[2 * NBLK + blockIdx.x] = sh[0][2] + sh[1][2] + sh[2][2] + sh[3][2];
    partials[3 * NBLK + blockIdx.x] = sh[0][3] + sh[1][3] + sh[2][3] + sh[3][3];
  }
}

// ---------------- finalize ----------------
__device__ double segSum(const double* __restrict__ p, int n, double* sh) {
  double a = 0.0;
  for (int i = threadIdx.x; i < n; i += 256) a += p[i];
  sh[threadIdx.x] = a;
  __syncthreads();
  for (int s = 128; s > 0; s >>= 1) {
    if ((int)threadIdx.x < s) sh[threadIdx.x] += sh[threadIdx.x + s];
    __syncthreads();
  }
  double r = sh[0];
  __syncthreads();
  return r;
}

__global__ __launch_bounds__(256) void finalize_kernel(
    const double* __restrict__ partials, const int* __restrict__ mel_lengths,
    float* __restrict__ out) {
  __shared__ double sh[256];
  double mel_sum  = segSum(partials, NBLK, sh);
  double gate_sum = segSum(partials + NBLK, NBLK, sh);
  double kl_sum   = segSum(partials + 2 * NBLK, NBLK, sh);
  double ent_sum  = segSum(partials + 3 * NBLK, NBLK, sh);
  if (threadIdx.x == 0) {
    long nv = 0;
    for (int b = 0; b < B_; ++b) nv += mel_lengths[b];
    double n_valid = (double)nv * (double)M_;
    float loss_mel  = (float)(mel_sum / n_valid);
    float loss_gate = (float)(gate_sum / (double)(B_ * T_));
    float kl  = (float)(kl_sum / (double)(B_ * T_));
    kl = fminf(kl, 150.0f);
    float ent = (float)(ent_sum / (double)(B_ * T_));
    float ratio = fmaxf(ent / 3.5f, 0.0f);
    float weight = (ent <= 3.5f) ? fmaxf(0.2f, 1.0f * ratio) : 1.0f;
    out[0] = loss_mel + loss_gate + weight * kl;
    out[1] = loss_mel;
    out[2] = loss_gate;
    out[3] = kl;
  }
}

extern "C" void kernel_launch(void* const* d_in, const int* in_sizes, int n_in,
                              void* d_out, int out_size, void* d_ws, size_t ws_size,
                              hipStream_t stream) {
  const float* mel_out_postnet = (const float*)d_in[0];
  const float* mel_out         = (const float*)d_in[1];
  const float* gate_out        = (const float*)d_in[2];
  const float* alignments      = (const float*)d_in[3];
  const float* mel_target      = (const float*)d_in[4];
  const float* gate_target     = (const float*)d_in[5];
  const int*   mel_lengths     = (const int*)d_in[6];
  const int*   text_lengths    = (const int*)d_in[7];
  float* out = (float*)d_out;

  // ws layout: tbl (25600*16B) | rowtbl (128000*16B) | partials (4*2000*8B)
  float4* tbl = (float4*)d_ws;
  float4* rowtbl = (float4*)((char*)d_ws + (size_t)TBL_N * 16);
  double* partials = (double*)((char*)d_ws + (size_t)(TBL_N + NROW) * 16);

  table_kernel<<<dim3((TBL_N * 64 + 255) / 256), dim3(256), 0, stream>>>(
      text_lengths, tbl);
  expand_kernel<<<dim3((NROW + 255) / 256), dim3(256), 0, stream>>>(
      tbl, text_lengths, mel_lengths, rowtbl);
  fused_kernel<<<dim3(NBLK), dim3(256), 0, stream>>>(
      (const float4*)mel_out, (const float4*)mel_out_postnet,
      (const float4*)mel_target, (const float4*)gate_out,
      (const float4*)gate_target, (const float4*)alignments,
      rowtbl, partials);
  finalize_kernel<<<dim3(1), dim3(256), 0, stream>>>(partials, mel_lengths, out);
}